// Round 11
// baseline (300.201 us; speedup 1.0000x reference)
//
#include <hip/hip_runtime.h>

// KacLayer: out[512][4096] = x @ W^T + b  +  Kac2( vec * Kac1( x ) )
//
//  kfused: blocks 0..11: per-8192-step window scheduler (unchanged from R10).
//          Election assigns dependency depth; one-shot level layout with +2
//          gap chunks between non-empty levels => any 3 consecutive chunks
//          column-disjoint. Records scattered to global (pad-prefilled).
//          Bit-exact reorder of commuting Givens rotations.
//          blocks 12..1163: fp32->bf16 convert of W and X into d_ws.
//  kgemm_bf: bf16 MFMA GEMM, 128x128 tile, BK=128, XOR-swizzled LDS,
//          runtime Ksplit (4 if ws allows, else 2) -> out + (nks-1) partials.
//  kwalk : 128 threads / block; EACH WAVE owns ONE private float row in LDS
//          (no barriers, halved per-wave issue work, b32 gathers ~conflict-
//          free). 3-stage pipeline per wave: records loaded +4, decoded+
//          gathered +2, rotated+scattered at 0. Epilogue adds partials.

#define DIM    4096
#define ROWS   512
#define NSTEPS 49152
#define WSTEPS 8192
#define NW2    (NSTEPS / WSTEPS)   // 6 windows per walk
#define NSLOT  (2 * NW2)           // 12 slots
#define MAXCHP 256
#define NSG    16                  // rank subgroups (one per wave)
#define CHUNK  128
#define SLOT   (MAXCHP * CHUNK)    // 32768 records per slot
#define MAXR   96
#define PADI   4096
#define PADJ   4097
#define KT     1024                // scheduler threads
#define SPT    (WSTEPS / KT)       // 8 steps per thread
#define NCVW   1024                // W-convert blocks
#define NCVX   128                 // X-convert blocks

typedef short  short8 __attribute__((ext_vector_type(8)));
typedef __bf16 bf16x8 __attribute__((ext_vector_type(8)));
typedef float  f32x4  __attribute__((ext_vector_type(4)));

__device__ inline short f2bf(float f) {
    unsigned u = __builtin_bit_cast(unsigned, f);
    u += 0x7FFFu + ((u >> 16) & 1u);
    return (short)(u >> 16);
}
__device__ inline short8 pack8(float4 a, float4 b) {
    short8 r;
    r[0] = f2bf(a.x); r[1] = f2bf(a.y); r[2] = f2bf(a.z); r[3] = f2bf(a.w);
    r[4] = f2bf(b.x); r[5] = f2bf(b.y); r[6] = f2bf(b.z); r[7] = f2bf(b.w);
    return r;
}
__device__ inline float bitf(unsigned u) { return __builtin_bit_cast(float, u); }
__device__ inline float ldf(const float* rw, int boff) {
    return *(const float*)((const char*)rw + boff);
}
__device__ inline void stf(float* rw, int boff, float v) {
    *(float*)((char*)rw + boff) = v;
}

// ---------------------------------------------------------------------------
// 1) fused scheduler (blocks 0..NSLOT-1) + bf16 convert (blocks NSLOT..)
// ---------------------------------------------------------------------------
__global__ __launch_bounds__(KT) void kfused(
    const int* __restrict__ i1, const int* __restrict__ j1,
    const float* __restrict__ c1, const float* __restrict__ s1,
    const int* __restrict__ i2, const int* __restrict__ j2,
    const float* __restrict__ c2, const float* __restrict__ s2,
    uint4* __restrict__ recs, int* __restrict__ cnts,
    int doconv, const float* __restrict__ W, const float* __restrict__ X,
    short* __restrict__ wb, short* __restrict__ xb) {

    // ---------------- convert path ----------------
    if (blockIdx.x >= NSLOT) {
        if (!doconv) return;
        const int cb = blockIdx.x - NSLOT;
        const float* src; short* dst; size_t base;
        if (cb < NCVW) { src = W; dst = wb; base = (size_t)cb * 16384; }
        else           { src = X; dst = xb; base = (size_t)(cb - NCVW) * 16384; }
        const size_t o = base + (size_t)threadIdx.x * 16;
        const float4* s4 = (const float4*)(src + o);
        const float4 a0 = s4[0], a1 = s4[1], a2 = s4[2], a3 = s4[3];
        *(short8*)(dst + o)     = pack8(a0, a1);
        *(short8*)(dst + o + 8) = pack8(a2, a3);
        return;
    }

    // ---------------- scheduler path ----------------
    __shared__ unsigned tbl[DIM];          // election keys      (16 KB)
    __shared__ unsigned spair[WSTEPS];     // li | lj<<16        (32 KB)
    __shared__ unsigned lvrk[WSTEPS];      // rank<<8 | level    (32 KB)
    __shared__ int lcnt[MAXR * NSG];       // per-(level,wave) counters (6 KB)
    __shared__ int ltot[MAXR], chbase[MAXR];
    __shared__ int nchunks;

    const int b    = blockIdx.x;           // 0..11
    const int walk = b / NW2;
    const int w    = b % NW2;
    const int t    = threadIdx.x;
    const int gb   = w * WSTEPS;
    const int sg   = t >> 6;               // wave id 0..15

    const int*   I = walk ? i2 : i1;
    const int*   J = walk ? j2 : j1;
    const float* C = walk ? c2 : c1;
    const float* S = walk ? s2 : s1;

    uint4* slotp = recs + (size_t)b * SLOT;

    // prefill slot region with identity-pad records (coalesced)
    {
        const uint4 padrec = { (unsigned)(PADI * 8), 0x3F800000u, 0u, (unsigned)(PADJ * 8) };
        for (int k = t; k < SLOT; k += KT) slotp[k] = padrec;
    }
    for (int s = t; s < WSTEPS; s += KT)
        spair[s] = (unsigned)I[gb + s] | ((unsigned)J[gb + s] << 16);
    for (int k = t; k < DIM; k += KT) tbl[k] = 0xFFFFFFFFu;
    for (int k = t; k < MAXR * NSG; k += KT) lcnt[k] = 0;
    __syncthreads();

    // ---- election: 2 barriers/round; level = DAG depth --------------------
    unsigned pmask = (1u << SPT) - 1u;
    for (int rr = 0; rr < MAXR; ++rr) {
        const unsigned rk = (unsigned)(MAXR - 1 - rr) << 13;
#pragma unroll
        for (int q = 0; q < SPT; ++q)
            if (pmask & (1u << q)) {
                const int s = q * KT + t;
                const unsigned sp = spair[s];
                const unsigned key = rk | (unsigned)s;
                atomicMin(&tbl[sp & 0xFFFFu], key);
                atomicMin(&tbl[sp >> 16], key);
            }
        __syncthreads();                                   // B1
#pragma unroll
        for (int q = 0; q < SPT; ++q)
            if (pmask & (1u << q)) {
                const int s = q * KT + t;
                const unsigned sp = spair[s];
                const unsigned key = rk | (unsigned)s;
                if (tbl[sp & 0xFFFFu] == key && tbl[sp >> 16] == key) {
                    const int rank = atomicAdd(&lcnt[rr * NSG + sg], 1);
                    lvrk[s] = ((unsigned)rank << 8) | (unsigned)rr;
                    pmask &= ~(1u << q);
                }
            }
        const int np = __syncthreads_count(pmask != 0);    // B2
        if (np == 0) break;
    }
    // safety net (statistically unreachable)
#pragma unroll
    for (int q = 0; q < SPT; ++q)
        if (pmask & (1u << q)) {
            const int s = q * KT + t;
            const int rank = atomicAdd(&lcnt[(MAXR - 1) * NSG + sg], 1);
            lvrk[s] = ((unsigned)rank << 8) | (unsigned)(MAXR - 1);
        }
    __syncthreads();

    // ---- one-shot layout --------------------------------------------------
    if (t < MAXR) {
        int run = 0;
        for (int g = 0; g < NSG; ++g) {
            const int v = lcnt[t * NSG + g];
            lcnt[t * NSG + g] = run;
            run += v;
        }
        ltot[t] = run;
    }
    __syncthreads();
    if (t < 64) {
        const int l = t;
        const int tot1 = ltot[l];
        const int w1 = (tot1 > 0) ? (((tot1 + 127) >> 7) + 2) : 0;
        int x1 = w1;
        for (int off = 1; off < 64; off <<= 1) {
            const int v = __shfl_up(x1, off);
            if (l >= off) x1 += v;
        }
        chbase[l] = x1 - w1;
        const int seg1 = __shfl(x1, 63);
        const int l2 = 64 + (l & 31);
        const int tot2 = ltot[l2];
        const int w2 = (tot2 > 0) ? (((tot2 + 127) >> 7) + 2) : 0;
        int x2 = w2;
        for (int off = 1; off < 32; off <<= 1) {
            const int v = __shfl_up(x2, off);
            if ((l & 31) >= off) x2 += v;
        }
        if (l < 32) chbase[l2] = seg1 + x2 - w2;
        if (l == 31) nchunks = seg1 + x2;
    }
    __syncthreads();
    if (t == 0) {
        int nc = nchunks;
        if (nc < 4) nc = 4;
        if (nc > MAXCHP) nc = MAXCHP;
        cnts[b] = nc * CHUNK;
    }

    // ---- record emission --------------------------------------------------
#pragma unroll
    for (int q = 0; q < SPT; ++q) {
        const int s = q * KT + t;
        const unsigned v = lvrk[s];
        const int lvl  = (int)(v & 0xFFu);
        const int rank = (int)(v >> 8) + lcnt[lvl * NSG + sg];
        const int p    = (chbase[lvl] + (rank >> 7)) * CHUNK + (rank & 127);
        if (p < SLOT) {
            const unsigned sp = spair[s];
            const int g = gb + s;
            uint4 r;
            r.x = (sp & 0xFFFFu) * 8u;
            r.y = __builtin_bit_cast(unsigned, C[g]);
            r.z = __builtin_bit_cast(unsigned, S[g]);
            r.w = (sp >> 16) * 8u;
            slotp[p] = r;
        }
    }
}

// ---------------------------------------------------------------------------
// 2a) bf16 GEMM: 128x128 tile, BK=128, runtime Ksplit nks
// ---------------------------------------------------------------------------
__global__ __launch_bounds__(256) void kgemm_bf(const short* __restrict__ Xb, const short* __restrict__ Wb,
                                                const float* __restrict__ bias, float* __restrict__ out,
                                                float* __restrict__ parts, int nks) {
    __shared__ short As[128 * 128];
    __shared__ short Bs[128 * 128];
    const int bid  = blockIdx.x;
    const int ks   = bid % nks;
    const int tile = bid / nks;                // 0..127
    const int bm   = (tile >> 5) * 128;
    const int bn   = (tile & 31) * 128;
    const int tid  = threadIdx.x;
    const int lane = tid & 63;
    const int wv   = tid >> 6;
    const int wr   = (wv >> 1) * 64;
    const int wc   = (wv & 1) * 64;
    const int fr   = lane & 15;
    const int ke   = (lane >> 4) * 8;

    f32x4 acc[4][4];
#pragma unroll
    for (int m = 0; m < 4; ++m)
#pragma unroll
        for (int n = 0; n < 4; ++n) acc[m][n] = (f32x4){0.f, 0.f, 0.f, 0.f};

    const int tr2 = tid >> 1;                  // staging row 0..127
    const int hh  = tid & 1;                   // 64-elem half
    const int wm  = tr2 & 7;                   // swizzle mask
    const short* gxa = Xb + (size_t)(bm + tr2) * DIM + hh * 64;
    const short* gwb = Wb + (size_t)(bn + tr2) * DIM + hh * 64;

    const int nkt = DIM / 128 / nks;
    const int kbase = ks * (DIM / nks);
    for (int kt = 0; kt < nkt; ++kt) {
        const int k0 = kbase + kt * 128;
        short8 ar[8], br[8];
#pragma unroll
        for (int q = 0; q < 8; ++q) ar[q] = *(const short8*)(gxa + k0 + q * 8);
#pragma unroll
        for (int q = 0; q < 8; ++q) br[q] = *(const short8*)(gwb + k0 + q * 8);
        __syncthreads();                       // previous tile's reads done
#pragma unroll
        for (int q = 0; q < 8; ++q) {
            const int sl = (hh * 8 + q) ^ wm;  // XOR-swizzled 16B slot
            *(short8*)&As[tr2 * 128 + sl * 8] = ar[q];
            *(short8*)&Bs[tr2 * 128 + sl * 8] = br[q];
        }
        __syncthreads();
#pragma unroll
        for (int kk = 0; kk < 128; kk += 32) {
            const int sbase = (kk + ke) >> 3;
            short8 af[4], bf[4];
#pragma unroll
            for (int m = 0; m < 4; ++m) {
                const int R = wr + m * 16 + fr;
                af[m] = *(const short8*)&As[R * 128 + ((sbase ^ (R & 7)) << 3)];
            }
#pragma unroll
            for (int n = 0; n < 4; ++n) {
                const int R = wc + n * 16 + fr;
                bf[n] = *(const short8*)&Bs[R * 128 + ((sbase ^ (R & 7)) << 3)];
            }
#pragma unroll
            for (int m = 0; m < 4; ++m)
#pragma unroll
                for (int n = 0; n < 4; ++n)
                    acc[m][n] = __builtin_amdgcn_mfma_f32_16x16x32_bf16(
                        __builtin_bit_cast(bf16x8, af[m]),
                        __builtin_bit_cast(bf16x8, bf[n]),
                        acc[m][n], 0, 0, 0);
        }
    }
    float* dst = ks ? (parts + (size_t)(ks - 1) * ROWS * DIM) : out;
#pragma unroll
    for (int n = 0; n < 4; ++n) {
        const int col = bn + wc + n * 16 + fr;
        const float bv = ks ? 0.f : bias[col];
#pragma unroll
        for (int m = 0; m < 4; ++m) {
            const int rbase = bm + wr + m * 16 + (lane >> 4) * 4;
#pragma unroll
            for (int r = 0; r < 4; ++r)
                dst[(size_t)(rbase + r) * DIM + col] = acc[m][n][r] + bv;
        }
    }
}

// ---------------------------------------------------------------------------
// 2b) fallback GEMM: fp32 staging, BM=64 BN=128, full K, 256 thr
// ---------------------------------------------------------------------------
#define LDT 72
__global__ __launch_bounds__(256) void kgemm_small(const float* __restrict__ X, const float* __restrict__ W,
                                                   const float* __restrict__ bias, float* __restrict__ out) {
    __shared__ short As[64 * LDT];
    __shared__ short Bs[128 * LDT];
    const int tid  = threadIdx.x;
    const int bn   = (blockIdx.x & 31) * 128;
    const int bm   = (blockIdx.x >> 5) * 64;
    const int lane = tid & 63;
    const int wv   = tid >> 6;
    const int wr   = (wv >> 1) * 32;
    const int wc   = (wv & 1) * 64;
    const int fr   = lane & 15;
    const int ke   = (lane >> 4) * 8;

    f32x4 acc[2][4];
#pragma unroll
    for (int m = 0; m < 2; ++m)
#pragma unroll
        for (int n = 0; n < 4; ++n) acc[m][n] = (f32x4){0.f, 0.f, 0.f, 0.f};

    const int tr = tid >> 2;
    const int tc = (tid & 3) << 4;

    for (int kt = 0; kt < DIM / 64; ++kt) {
        const int k0 = kt * 64;
        float4 ra[4], rb[2][4];
        {
            const float4* ga = (const float4*)(X + (size_t)(bm + tr) * DIM + k0 + tc);
#pragma unroll
            for (int q = 0; q < 4; ++q) ra[q] = ga[q];
#pragma unroll
            for (int h = 0; h < 2; ++h) {
                const float4* gw = (const float4*)(W + (size_t)(bn + h * 64 + tr) * DIM + k0 + tc);
#pragma unroll
                for (int q = 0; q < 4; ++q) rb[h][q] = gw[q];
            }
        }
        __syncthreads();
        *(short8*)&As[tr * LDT + tc]     = pack8(ra[0], ra[1]);
        *(short8*)&As[tr * LDT + tc + 8] = pack8(ra[2], ra[3]);
#pragma unroll
        for (int h = 0; h < 2; ++h) {
            *(short8*)&Bs[(h * 64 + tr) * LDT + tc]     = pack8(rb[h][0], rb[h][1]);
            *(short8*)&Bs[(h * 64 + tr) * LDT + tc + 8] = pack8(rb[h][2], rb[h][3]);
        }
        __syncthreads();
#pragma unroll
        for (int kk = 0; kk < 64; kk += 32) {
            short8 af[2], bf[4];
#pragma unroll
            for (int m = 0; m < 2; ++m)
                af[m] = *(const short8*)&As[(wr + m * 16 + fr) * LDT + kk + ke];
#pragma unroll
            for (int n = 0; n < 4; ++n)
                bf[n] = *(const short8*)&Bs[(wc + n * 16 + fr) * LDT + kk + ke];
#pragma unroll
            for (int m = 0; m < 2; ++m)
#pragma unroll
                for (int n = 0; n < 4; ++n)
                    acc[m][n] = __builtin_amdgcn_mfma_f32_16x16x32_bf16(
                        __builtin_bit_cast(bf16x8, af[m]),
                        __builtin_bit_cast(bf16x8, bf[n]),
                        acc[m][n], 0, 0, 0);
        }
    }
#pragma unroll
    for (int n = 0; n < 4; ++n) {
        const int col = bn + wc + n * 16 + fr;
        const float bv = bias[col];
#pragma unroll
        for (int m = 0; m < 2; ++m) {
            const int rbase = bm + wr + m * 16 + (lane >> 4) * 4;
#pragma unroll
            for (int r = 0; r < 4; ++r)
                out[(size_t)(rbase + r) * DIM + col] = acc[m][n][r] + bv;
        }
    }
}

// ---------------------------------------------------------------------------
// 3) walk kernel: 128 thr / block, ONE PRIVATE ROW PER WAVE (no barriers)
// ---------------------------------------------------------------------------
__global__ __launch_bounds__(128) void kwalk(const float* __restrict__ X, const float* __restrict__ vec,
                                             const uint4* __restrict__ recs, const int* __restrict__ cnts,
                                             const float* __restrict__ parts, int nparts,
                                             float* __restrict__ out) {
    __shared__ float rowbuf[2][DIM + 8];
    const int wv   = threadIdx.x >> 6;
    const int lane = threadIdx.x & 63;
    float* rw = rowbuf[wv];
    const int row = blockIdx.x * 2 + wv;

    {   // init own row (vectorized); pad slots for identity records
        const float4* xr = (const float4*)(X + (size_t)row * DIM);
        float4* r4 = (float4*)rw;
        for (int c = lane; c < DIM / 4; c += 64) r4[c] = xr[c];
        if (lane < 2) rw[DIM + lane] = 0.f;    // idx 4096/4097 = PAD targets
    }

    const int cnreg = cnts[lane < NSLOT ? lane : 0];

    for (int slot = 0; slot < NSLOT; ++slot) {
        if (slot == NW2) {      // between walks: yp = vec * yp (own row only)
            const float4* v4 = (const float4*)vec;
            float4* r4 = (float4*)rw;
            for (int c = lane; c < DIM / 4; c += 64) {
                float4 tv = r4[c]; const float4 v = v4[c];
                tv.x *= v.x; tv.y *= v.y; tv.z *= v.z; tv.w *= v.w;
                r4[c] = tv;
            }
        }
        const int nit = __shfl(cnreg, slot) >> 7;
        const uint4* base = recs + (size_t)slot * SLOT;

        // prologue: chunks 0,1 decoded+gathered, chunks 2,3 in record ring
        uint4 rd0A = base[256 + lane], rd0B = base[256 + 64 + lane];
        uint4 rd1A = base[384 + lane], rd1B = base[384 + 64 + lane];
        const uint4 c0A = base[lane],       c0B = base[64 + lane];
        const uint4 c1A = base[128 + lane], c1B = base[192 + lane];

        int   i0 = (int)(c0A.x >> 1), j0 = (int)(c0A.w >> 1);  // float byte offs
        int   i1 = (int)(c0B.x >> 1), j1 = (int)(c0B.w >> 1);
        float cc0 = bitf(c0A.y), ss0 = bitf(c0A.z);
        float cc1 = bitf(c0B.y), ss1 = bitf(c0B.z);
        float gi0 = ldf(rw, i0), gj0 = ldf(rw, j0);
        float gi1 = ldf(rw, i1), gj1 = ldf(rw, j1);

        int   ni0 = (int)(c1A.x >> 1), nj0 = (int)(c1A.w >> 1);
        int   ni1 = (int)(c1B.x >> 1), nj1 = (int)(c1B.w >> 1);
        float nc0 = bitf(c1A.y), ns0 = bitf(c1A.z);
        float nc1 = bitf(c1B.y), ns1 = bitf(c1B.z);
        float hi0 = ldf(rw, ni0), hj0 = ldf(rw, nj0);
        float hi1 = ldf(rw, ni1), hj1 = ldf(rw, nj1);

#pragma unroll 4
        for (int k = 0; k < nit; ++k) {
            // stage L: records for chunk k+4 (clamped -> trailing pads)
            const int kc = (k + 4 < nit) ? (k + 4) : (nit - 1);
            const uint4 mA = base[(size_t)kc * 128 + lane];
            const uint4 mB = base[(size_t)kc * 128 + 64 + lane];

            // stage G: decode + gather chunk k+2 (3 consecutive disjoint)
            const int   ti0 = (int)(rd0A.x >> 1), tj0 = (int)(rd0A.w >> 1);
            const int   ti1 = (int)(rd0B.x >> 1), tj1 = (int)(rd0B.w >> 1);
            const float tc0 = bitf(rd0A.y), ts0 = bitf(rd0A.z);
            const float tc1 = bitf(rd0B.y), ts1 = bitf(rd0B.z);
            const float tgi0 = ldf(rw, ti0), tgj0 = ldf(rw, tj0);
            const float tgi1 = ldf(rw, ti1), tgj1 = ldf(rw, tj1);

            // stage C: rotate + scatter chunk k (2 records x 1 row per lane)
            const float wi0 = fmaf(cc0, gi0,  ss0 * gj0);
            const float wj0 = fmaf(cc0, gj0, -ss0 * gi0);
            const float wi1 = fmaf(cc1, gi1,  ss1 * gj1);
            const float wj1 = fmaf(cc1, gj1, -ss1 * gi1);
            stf(rw, i0, wi0); stf(rw, j0, wj0);
            stf(rw, i1, wi1); stf(rw, j1, wj1);

            // rotate pipeline
            i0 = ni0; j0 = nj0; i1 = ni1; j1 = nj1;
            cc0 = nc0; ss0 = ns0; cc1 = nc1; ss1 = ns1;
            gi0 = hi0; gj0 = hj0; gi1 = hi1; gj1 = hj1;
            ni0 = ti0; nj0 = tj0; ni1 = ti1; nj1 = tj1;
            nc0 = tc0; ns0 = ts0; nc1 = tc1; ns1 = ts1;
            hi0 = tgi0; hj0 = tgj0; hi1 = tgi1; hj1 = tgj1;
            rd0A = rd1A; rd0B = rd1B; rd1A = mA; rd1B = mB;
        }
    }

    // epilogue: out[row] += walked row + split-K partials
    float4* o4 = (float4*)(out + (size_t)row * DIM);
    const float4* r4 = (const float4*)rw;
    const size_t PS = (size_t)ROWS * DIM / 4;
    const float4* q = (const float4*)parts + (size_t)row * (DIM / 4);
    for (int c = lane; c < DIM / 4; c += 64) {
        float4 t = o4[c];
        const float4 s = r4[c];
        t.x += s.x; t.y += s.y; t.z += s.z; t.w += s.w;
        for (int p = 0; p < nparts; ++p) {
            const float4 a = q[c + (size_t)p * PS];
            t.x += a.x; t.y += a.y; t.z += a.z; t.w += a.w;
        }
        o4[c] = t;
    }
}

// ---------------------------------------------------------------------------
extern "C" void kernel_launch(void* const* d_in, const int* in_sizes, int n_in,
                              void* d_out, int out_size, void* d_ws, size_t ws_size,
                              hipStream_t stream) {
    const float* X    = (const float*)d_in[0];
    const float* W    = (const float*)d_in[1];
    const float* bias = (const float*)d_in[2];
    const float* vec  = (const float*)d_in[3];
    const int*   i1   = (const int*)d_in[4];
    const int*   j1   = (const int*)d_in[5];
    const float* c1   = (const float*)d_in[6];
    const float* s1   = (const float*)d_in[7];
    const int*   i2   = (const int*)d_in[8];
    const int*   j2   = (const int*)d_in[9];
    const float* c2   = (const float*)d_in[10];
    const float* s2   = (const float*)d_in[11];
    float* out = (float*)d_out;

    const size_t RD         = (size_t)ROWS * DIM * 4;            // 8 MiB
    const size_t WBB        = (size_t)DIM * DIM * 2;             // 32 MiB
    const size_t XBB        = (size_t)ROWS * DIM * 2;            // 4 MiB
    const size_t recs_bytes = (size_t)NSLOT * SLOT * 16;         // 6.29 MiB
    const size_t off_parts  = recs_bytes + 4096;

    // tiered Ksplit by workspace size
    int nks = 0;
    size_t off_wb = 0;
    {
        const size_t need4 = off_parts + 3 * RD + WBB + XBB;
        const size_t need2 = off_parts + 1 * RD + WBB + XBB;
        if      (ws_size >= need4) { nks = 4; off_wb = off_parts + 3 * RD; }
        else if (ws_size >= need2) { nks = 2; off_wb = off_parts + 1 * RD; }
    }

    uint4* recs  = (uint4*)d_ws;
    int*   cnts  = (int*)((char*)d_ws + recs_bytes);
    float* parts = (float*)((char*)d_ws + off_parts);
    short* wbuf  = (short*)((char*)d_ws + off_wb);
    short* xbuf  = (short*)((char*)d_ws + off_wb + WBB);
    const bool bf = (nks > 0);

    hipLaunchKernelGGL(kfused, dim3(NSLOT + (bf ? (NCVW + NCVX) : 0)), dim3(KT), 0, stream,
                       i1, j1, c1, s1, i2, j2, c2, s2, recs, cnts,
                       bf ? 1 : 0, W, X, wbuf, xbuf);
    if (bf)
        hipLaunchKernelGGL(kgemm_bf, dim3(128 * nks), dim3(256), 0, stream,
                           xbuf, wbuf, bias, out, parts, nks);
    else
        hipLaunchKernelGGL(kgemm_small, dim3(256), dim3(256), 0, stream, X, W, bias, out);
    hipLaunchKernelGGL(kwalk, dim3(ROWS / 2), dim3(128), 0, stream,
                       X, vec, recs, cnts, parts, bf ? (nks - 1) : 0, out);
}